// Round 10
// baseline (688.147 us; speedup 1.0000x reference)
//
#include <hip/hip_runtime.h>
#include <math.h>

// ---------------------------------------------------------------------------
// Graph attention (per-dst softmax) + weighted segment_max aggregation +
// gated update + per-graph sum readout + linear classifier.
//
// 6-node pipeline (cuts 3 dispatches vs round-4; each graph node costs
// cross-XCD cache maintenance on MI355X):
//   0. memset   : deg = 0                       (deg only; cur/hg zeroed in K1)
//   1. k_prep   : [block-range multiplexed] ps/pd projections | deg histogram
//                 | zero cur+hg
//   2. k_scan1  : loffs = per-1024-tile EXCLUSIVE scan of deg; bsum[tile]
//   3. k_scatter: inline LDS scan of bsum -> bpre; ssrc[glob_off + rank] = src
//   4. k_fused  : inline bpre; per wave KNODES dst nodes: lane-parallel
//                 softmax (shfl bcast), 4x-unrolled float4 row gathers with
//                 register fmax, gated update, register graph-sum, atomic
//                 flush per graph-run
//   5. k_out    : out[b,c] = lrelu(hg[b,:]) @ Wl[:,c] + bl[c]
// ---------------------------------------------------------------------------

#define SLOPE 0.01f
#define KNODES 8
#define MAXT 192   // max scan tiles for inline bpre (supports N <= 196608)

__device__ __forceinline__ float lrelu(float x) { return x >= 0.f ? x : SLOPE * x; }

__device__ __forceinline__ float wrsum(float v) {
#pragma unroll
    for (int m = 32; m >= 1; m >>= 1) v += __shfl_xor(v, m, 64);
    return v;
}
__device__ __forceinline__ float wrmax(float v) {
#pragma unroll
    for (int m = 32; m >= 1; m >>= 1) v = fmaxf(v, __shfl_xor(v, m, 64));
    return v;
}

// Exclusive scan of bsum[0..nT) into LDS lb[] (wave 0 only; 3 elems/lane).
// MUST be called by all threads of the block before any early return.
__device__ __forceinline__ void compute_bpre(const unsigned* __restrict__ bsum,
                                             int nT, unsigned* lb) {
    if (threadIdx.x < 64) {
        int l = threadIdx.x;
        unsigned a0 = (3 * l     < nT) ? bsum[3 * l]     : 0u;
        unsigned a1 = (3 * l + 1 < nT) ? bsum[3 * l + 1] : 0u;
        unsigned a2 = (3 * l + 2 < nT) ? bsum[3 * l + 2] : 0u;
        unsigned tot = a0 + a1 + a2, x = tot;
#pragma unroll
        for (int d = 1; d < 64; d <<= 1) {
            unsigned y = __shfl_up(x, d, 64);
            if (l >= d) x += y;
        }
        unsigned excl = x - tot;
        if (3 * l     < nT) lb[3 * l]     = excl;
        if (3 * l + 1 < nT) lb[3 * l + 1] = excl + a0;
        if (3 * l + 2 < nT) lb[3 * l + 2] = excl + a0 + a1;
    }
    __syncthreads();
}

// ---- 1. k_prep: block-range multiplexed {ps/pd | hist | zero} -------------
__global__ __launch_bounds__(256) void k_prep(
    const float* __restrict__ H, const float* __restrict__ Wa,
    const int* __restrict__ dst,
    float* __restrict__ ps, float* __restrict__ pd,
    unsigned* __restrict__ deg,
    unsigned* __restrict__ zbase, size_t zn,   // cur+hg zero region (elems)
    int N, int D, int E, int nb_ps, int nb_hist) {
    int b = blockIdx.x;
    if (b < nb_ps) {
        // attention projections: one wave per node, float4 loads
        int wid  = b * 4 + (threadIdx.x >> 6);
        int lane = threadIdx.x & 63;
        if (wid >= N) return;
        const float4* row = (const float4*)(H + (size_t)wid * D);
        const float4* wa0 = (const float4*)Wa;
        const float4* wa1 = (const float4*)(Wa + D);   // D%4==0
        int nv = D >> 2;
        float s0 = 0.f, s1 = 0.f;
        for (int v = lane; v < nv; v += 64) {
            float4 h = row[v], a = wa0[v], c = wa1[v];
            s0 += h.x * a.x + h.y * a.y + h.z * a.z + h.w * a.w;
            s1 += h.x * c.x + h.y * c.y + h.z * c.z + h.w * c.w;
        }
        s0 = wrsum(s0);
        s1 = wrsum(s1);
        if (lane == 0) { ps[wid] = s0; pd[wid] = s1; }
    } else if (b < nb_ps + nb_hist) {
        int e = (b - nb_ps) * 256 + threadIdx.x;
        if (e < E) atomicAdd(&deg[dst[e]], 1u);
    } else {
        // grid-stride zero of cur+hg
        int    nbz    = gridDim.x - nb_ps - nb_hist;
        size_t i      = (size_t)(b - nb_ps - nb_hist) * 256 + threadIdx.x;
        size_t stride = (size_t)nbz * 256;
        for (; i < zn; i += stride) zbase[i] = 0u;
    }
}

// ---- 2. per-tile exclusive scan -------------------------------------------
// loffs[i] = exclusive prefix of deg within i's 1024-tile; bsum[tile] = total.
__global__ __launch_bounds__(256) void k_scan1(
    const unsigned* __restrict__ deg, unsigned* __restrict__ loffs,
    unsigned* __restrict__ bsum, int N) {
    __shared__ unsigned wsum[4];
    int t = threadIdx.x, b = blockIdx.x;
    int base = b * 1024 + t * 4;
    unsigned v[4];
#pragma unroll
    for (int j = 0; j < 4; j++) { int i = base + j; v[j] = (i < N) ? deg[i] : 0u; }
    unsigned p0 = v[0], p1 = p0 + v[1], p2 = p1 + v[2];
    unsigned tot = p2 + v[3];
    unsigned x = tot;
    int lane = t & 63, w = t >> 6;
#pragma unroll
    for (int d = 1; d < 64; d <<= 1) { unsigned y = __shfl_up(x, d, 64); if (lane >= d) x += y; }
    if (lane == 63) wsum[w] = x;
    __syncthreads();
    unsigned woff = 0;
    for (int i = 0; i < w; i++) woff += wsum[i];
    unsigned excl = woff + x - tot;   // exclusive prefix of this thread's 4 elems
    unsigned o[4] = {excl, excl + p0, excl + p1, excl + p2};
#pragma unroll
    for (int j = 0; j < 4; j++) { int i = base + j; if (i < N) loffs[i] = o[j]; }
    if (t == 255) bsum[b] = excl + tot;  // tile total
}

// ---- 3. scatter edges into dst-sorted order (inline bpre) -----------------
__global__ __launch_bounds__(256) void k_scatter(
    const int* __restrict__ src, const int* __restrict__ dst,
    const unsigned* __restrict__ loffs, const unsigned* __restrict__ bsum,
    unsigned* __restrict__ cur, int* __restrict__ ssrc, int E, int nT) {
    __shared__ unsigned lb[MAXT];
    compute_bpre(bsum, nT, lb);
    int e = blockIdx.x * 256 + threadIdx.x;
    if (e >= E) return;
    int d = dst[e];
    unsigned base = loffs[d] + lb[d >> 10];
    unsigned r = atomicAdd(&cur[d], 1u);
    ssrc[base + r] = src[e];
}

// ---- 4. fused softmax + weighted segment_max + gate + graph-sum -----------
// One wave per KNODES consecutive dst nodes. Lane owns float4 #lane and
// (if q1) float4 #(64+lane). Requires D%4==0, D<=512.
__global__ __launch_bounds__(256) void k_fused(
    const float* __restrict__ H, const float* __restrict__ eta,
    const float* __restrict__ ps, const float* __restrict__ pd,
    const float* __restrict__ battn,
    const unsigned* __restrict__ loffs, const unsigned* __restrict__ bsum,
    const int* __restrict__ ssrc, const int* __restrict__ gid,
    float* __restrict__ hg, int N, int D, int E, int nT) {
    __shared__ unsigned lb[MAXT];
    compute_bpre(bsum, nT, lb);          // all threads reach the sync inside

    int wid  = (blockIdx.x * blockDim.x + threadIdx.x) >> 6;
    int lane = threadIdx.x & 63;
    int n0 = wid * KNODES;
    if (n0 >= N) return;
    int n1 = min(n0 + KNODES, N);
    int nv = D >> 2;
    bool q0 = lane < nv;
    bool q1 = (64 + lane) < nv;
    float b0 = battn[0];

    float sx = 0.f, sy = 0.f, sz = 0.f, sw = 0.f;
    float tx = 0.f, ty = 0.f, tz = 0.f, tw = 0.f;
    int curg = gid[n0];

    for (int n = n0; n < n1; ++n) {
        unsigned e0 = loffs[n] + lb[n >> 10];
        unsigned e1 = (n + 1 < N) ? (loffs[n + 1] + lb[(n + 1) >> 10]) : (unsigned)E;
        int degn = (int)(e1 - e0);
        const float4* hrow = (const float4*)(H + (size_t)n * D);
        float4 h0 = {0, 0, 0, 0}, h1 = {0, 0, 0, 0};
        if (q0) h0 = hrow[lane];
        if (q1) h1 = hrow[64 + lane];
        float hx = h0.x, hy = h0.y, hz = h0.z, hw = h0.w;
        float gx = h1.x, gy = h1.y, gz = h1.z, gw = h1.w;
        if (degn > 0) {
            float pdn = pd[n] + b0;
            float ax = -INFINITY, ay = -INFINITY, az = -INFINITY, aw = -INFINITY;
            float bx = -INFINITY, by = -INFINITY, bz = -INFINITY, bw = -INFINITY;
            if (degn <= 64) {
                // lane-parallel softmax, one edge per lane
                int   sn_l = (lane < degn) ? ssrc[e0 + lane] : 0;
                float w_l  = (lane < degn) ? lrelu(ps[sn_l] + pdn) : -INFINITY;
                float m    = wrmax(w_l);
                float ex   = (lane < degn) ? expf(w_l - m) : 0.f;
                float s    = wrsum(ex);
                float a_l  = ex * (1.f / s);
                // 4/2/1 unroll ladder: up to 4 independent row gathers in
                // flight per lane (fmax accumulation is order-free)
                int e = 0;
                for (; e + 3 < degn; e += 4) {
                    float a0s = __shfl(a_l, e, 64),     a1s = __shfl(a_l, e + 1, 64);
                    float a2s = __shfl(a_l, e + 2, 64), a3s = __shfl(a_l, e + 3, 64);
                    int   s0i = __shfl(sn_l, e, 64),     s1i = __shfl(sn_l, e + 1, 64);
                    int   s2i = __shfl(sn_l, e + 2, 64), s3i = __shfl(sn_l, e + 3, 64);
                    const float4* r0 = (const float4*)(H + (size_t)s0i * D);
                    const float4* r1 = (const float4*)(H + (size_t)s1i * D);
                    const float4* r2 = (const float4*)(H + (size_t)s2i * D);
                    const float4* r3 = (const float4*)(H + (size_t)s3i * D);
                    if (q0) {
                        float4 u0 = r0[lane], u1 = r1[lane], u2 = r2[lane], u3 = r3[lane];
                        ax = fmaxf(fmaxf(fmaxf(ax, a0s * u0.x), a1s * u1.x), fmaxf(a2s * u2.x, a3s * u3.x));
                        ay = fmaxf(fmaxf(fmaxf(ay, a0s * u0.y), a1s * u1.y), fmaxf(a2s * u2.y, a3s * u3.y));
                        az = fmaxf(fmaxf(fmaxf(az, a0s * u0.z), a1s * u1.z), fmaxf(a2s * u2.z, a3s * u3.z));
                        aw = fmaxf(fmaxf(fmaxf(aw, a0s * u0.w), a1s * u1.w), fmaxf(a2s * u2.w, a3s * u3.w));
                    }
                    if (q1) {
                        float4 u0 = r0[64 + lane], u1 = r1[64 + lane], u2 = r2[64 + lane], u3 = r3[64 + lane];
                        bx = fmaxf(fmaxf(fmaxf(bx, a0s * u0.x), a1s * u1.x), fmaxf(a2s * u2.x, a3s * u3.x));
                        by = fmaxf(fmaxf(fmaxf(by, a0s * u0.y), a1s * u1.y), fmaxf(a2s * u2.y, a3s * u3.y));
                        bz = fmaxf(fmaxf(fmaxf(bz, a0s * u0.z), a1s * u1.z), fmaxf(a2s * u2.z, a3s * u3.z));
                        bw = fmaxf(fmaxf(fmaxf(bw, a0s * u0.w), a1s * u1.w), fmaxf(a2s * u2.w, a3s * u3.w));
                    }
                }
                for (; e + 1 < degn; e += 2) {
                    float a0s = __shfl(a_l, e, 64), a1s = __shfl(a_l, e + 1, 64);
                    int   s0i = __shfl(sn_l, e, 64), s1i = __shfl(sn_l, e + 1, 64);
                    const float4* r0 = (const float4*)(H + (size_t)s0i * D);
                    const float4* r1 = (const float4*)(H + (size_t)s1i * D);
                    if (q0) {
                        float4 u0 = r0[lane], u1 = r1[lane];
                        ax = fmaxf(fmaxf(ax, a0s * u0.x), a1s * u1.x);
                        ay = fmaxf(fmaxf(ay, a0s * u0.y), a1s * u1.y);
                        az = fmaxf(fmaxf(az, a0s * u0.z), a1s * u1.z);
                        aw = fmaxf(fmaxf(aw, a0s * u0.w), a1s * u1.w);
                    }
                    if (q1) {
                        float4 u0 = r0[64 + lane], u1 = r1[64 + lane];
                        bx = fmaxf(fmaxf(bx, a0s * u0.x), a1s * u1.x);
                        by = fmaxf(fmaxf(by, a0s * u0.y), a1s * u1.y);
                        bz = fmaxf(fmaxf(bz, a0s * u0.z), a1s * u1.z);
                        bw = fmaxf(fmaxf(bw, a0s * u0.w), a1s * u1.w);
                    }
                }
                if (e < degn) {
                    float a  = __shfl(a_l, e, 64);
                    int   sn = __shfl(sn_l, e, 64);
                    const float4* srow = (const float4*)(H + (size_t)sn * D);
                    if (q0) {
                        float4 v0 = srow[lane];
                        ax = fmaxf(ax, a * v0.x); ay = fmaxf(ay, a * v0.y);
                        az = fmaxf(az, a * v0.z); aw = fmaxf(aw, a * v0.w);
                    }
                    if (q1) {
                        float4 v1 = srow[64 + lane];
                        bx = fmaxf(bx, a * v1.x); by = fmaxf(by, a * v1.y);
                        bz = fmaxf(bz, a * v1.z); bw = fmaxf(bw, a * v1.w);
                    }
                }
            } else {
                // rare high-degree fallback: recompute scores
                float mm = -INFINITY;
                for (unsigned e = e0 + lane; e < e1; e += 64)
                    mm = fmaxf(mm, lrelu(ps[ssrc[e]] + pdn));
                float m = wrmax(mm);
                float ssum = 0.f;
                for (unsigned e = e0 + lane; e < e1; e += 64)
                    ssum += expf(lrelu(ps[ssrc[e]] + pdn) - m);
                float s = wrsum(ssum), inv = 1.f / s;
                for (unsigned e = e0; e < e1; ++e) {
                    int sn = ssrc[e];
                    float a = expf(lrelu(ps[sn] + pdn) - m) * inv;
                    const float4* srow = (const float4*)(H + (size_t)sn * D);
                    if (q0) {
                        float4 v0 = srow[lane];
                        ax = fmaxf(ax, a * v0.x); ay = fmaxf(ay, a * v0.y);
                        az = fmaxf(az, a * v0.z); aw = fmaxf(aw, a * v0.w);
                    }
                    if (q1) {
                        float4 v1 = srow[64 + lane];
                        bx = fmaxf(bx, a * v1.x); by = fmaxf(by, a * v1.y);
                        bz = fmaxf(bz, a * v1.z); bw = fmaxf(bw, a * v1.w);
                    }
                }
            }
            float et = eta[n], om = 1.f - et;
            hx = et * h0.x + om * ax; hy = et * h0.y + om * ay;
            hz = et * h0.z + om * az; hw = et * h0.w + om * aw;
            gx = et * h1.x + om * bx; gy = et * h1.y + om * by;
            gz = et * h1.z + om * bz; gw = et * h1.w + om * bw;
        }
        // register graph-sum; flush on graph-id change (gid sorted)
        int g = gid[n];
        if (g != curg) {
            float* row = hg + (size_t)curg * D;
            int c = 4 * lane;
            if (q0) {
                atomicAdd(&row[c + 0], sx); atomicAdd(&row[c + 1], sy);
                atomicAdd(&row[c + 2], sz); atomicAdd(&row[c + 3], sw);
            }
            if (q1) {
                int c1 = 4 * (64 + lane);
                atomicAdd(&row[c1 + 0], tx); atomicAdd(&row[c1 + 1], ty);
                atomicAdd(&row[c1 + 2], tz); atomicAdd(&row[c1 + 3], tw);
            }
            sx = sy = sz = sw = tx = ty = tz = tw = 0.f;
            curg = g;
        }
        sx += hx; sy += hy; sz += hz; sw += hw;
        if (q1) { tx += gx; ty += gy; tz += gz; tw += gw; }
    }
    float* row = hg + (size_t)curg * D;
    int c = 4 * lane;
    if (q0) {
        atomicAdd(&row[c + 0], sx); atomicAdd(&row[c + 1], sy);
        atomicAdd(&row[c + 2], sz); atomicAdd(&row[c + 3], sw);
    }
    if (q1) {
        int c1 = 4 * (64 + lane);
        atomicAdd(&row[c1 + 0], tx); atomicAdd(&row[c1 + 1], ty);
        atomicAdd(&row[c1 + 2], tz); atomicAdd(&row[c1 + 3], tw);
    }
}

// ---- 5. classifier --------------------------------------------------------
__global__ __launch_bounds__(64) void k_out(
    const float* __restrict__ hg, const float* __restrict__ Wl,
    const float* __restrict__ bl, float* __restrict__ out,
    int D, int C) {
    int b = blockIdx.x;
    int c = threadIdx.x;
    if (c >= C) return;
    const float* row = hg + (size_t)b * D;
    float acc = 0.f;
    for (int d = 0; d < D; ++d)
        acc += lrelu(row[d]) * Wl[(size_t)d * C + c];
    out[(size_t)b * C + c] = acc + bl[c];
}

// ---------------------------------------------------------------------------
extern "C" void kernel_launch(void* const* d_in, const int* in_sizes, int n_in,
                              void* d_out, int out_size, void* d_ws, size_t ws_size,
                              hipStream_t stream) {
    const float* H   = (const float*)d_in[0];
    const float* eta = (const float*)d_in[1];
    const float* Wa  = (const float*)d_in[2];
    const float* ba  = (const float*)d_in[3];
    const float* Wl  = (const float*)d_in[4];
    const float* bl  = (const float*)d_in[5];
    const int*   src = (const int*)d_in[6];
    const int*   dst = (const int*)d_in[7];
    const int*   gid = (const int*)d_in[8];

    const int N = in_sizes[1];          // eta is [N,1]
    const int D = in_sizes[2] / 2;      // W_attn is [2D,1]
    const int C = in_sizes[5];          // b_lin is [C]
    const int E = in_sizes[6];          // src is [E]
    const int B = out_size / C;         // out is [B,C]

    // workspace layout (~8 MB): ps pd deg | cur hg (zeroed in K1) | loffs bsum ssrc
    char* w = (char*)d_ws;
    float*    ps    = (float*)w;    w += (size_t)N * 4;
    float*    pd    = (float*)w;    w += (size_t)N * 4;
    unsigned* deg   = (unsigned*)w; w += (size_t)N * 4;   // memset-zeroed
    unsigned* cur   = (unsigned*)w; w += (size_t)N * 4;   // K1-zeroed
    float*    hg    = (float*)w;    w += (size_t)B * D * 4; // K1-zeroed
    unsigned* loffs = (unsigned*)w; w += (size_t)N * 4;
    unsigned* bsum  = (unsigned*)w; w += 256 * 4;         // nT <= MAXT=192
    int*      ssrc  = (int*)w;      w += (size_t)E * 4;

    hipMemsetAsync(deg, 0, (size_t)N * 4, stream);

    const int nT      = (N + 1023) / 1024;   // requires nT <= MAXT
    const int nb_ps   = (N + 3) / 4;
    const int nb_hist = (E + 255) / 256;
    const int nb_zero = 256;
    const size_t zn   = (size_t)N + (size_t)B * D;  // cur + hg elems

    k_prep<<<dim3(nb_ps + nb_hist + nb_zero), dim3(256), 0, stream>>>(
        H, Wa, dst, ps, pd, deg, cur, zn, N, D, E, nb_ps, nb_hist);
    k_scan1<<<dim3(nT), dim3(256), 0, stream>>>(deg, loffs, bsum, N);
    k_scatter<<<dim3((E + 255) / 256), dim3(256), 0, stream>>>(
        src, dst, loffs, bsum, cur, ssrc, E, nT);
    {
        int waves  = (N + KNODES - 1) / KNODES;
        int blocks = (waves + 3) / 4;   // 4 waves per 256-thread block
        k_fused<<<dim3(blocks), dim3(256), 0, stream>>>(
            H, eta, ps, pd, ba, loffs, bsum, ssrc, gid, hg, N, D, E, nT);
    }
    k_out<<<dim3(B), dim3(64), 0, stream>>>(hg, Wl, bl, (float*)d_out, D, C);
}

// Round 11
// 606.871 us; speedup vs baseline: 1.1339x; 1.1339x over previous
//
#include <hip/hip_runtime.h>
#include <math.h>

// ---------------------------------------------------------------------------
// Graph attention (per-dst softmax) + weighted segment_max aggregation +
// gated update + per-graph sum readout + linear classifier.
//
// Pipeline (6 dispatches):
//   0. memset   : deg+hg = 0 (contiguous)
//   1. k_prep   : [block-range multiplexed] ps/pd projections | deg histogram
//                 which ALSO records each edge's rank (erank) -> scatter needs
//                 no atomics
//   2. k_scan1  : loffs = per-1024-tile EXCLUSIVE scan of deg; bsum[tile]
//   3. k_scatter: inline LDS scan of bsum -> bpre; pure computed-address write
//                 ssrc[loffs+bpre+erank] = src  (NO atomics)
//   4. k_fused  : inline bpre; per wave KNODES dst nodes: lane-parallel
//                 softmax (shfl bcast), 2x-unrolled float4 row gathers with
//                 register fmax (measured best: 255us @ VGPR32), gated update,
//                 register graph-sum, atomic flush per graph-run
//   5. k_out    : out[b,c] via 4 waves splitting D + LDS reduce
// ---------------------------------------------------------------------------

#define SLOPE 0.01f
#define KNODES 8
#define MAXT 192   // max scan tiles for inline bpre (supports N <= 196608)

__device__ __forceinline__ float lrelu(float x) { return x >= 0.f ? x : SLOPE * x; }

__device__ __forceinline__ float wrsum(float v) {
#pragma unroll
    for (int m = 32; m >= 1; m >>= 1) v += __shfl_xor(v, m, 64);
    return v;
}
__device__ __forceinline__ float wrmax(float v) {
#pragma unroll
    for (int m = 32; m >= 1; m >>= 1) v = fmaxf(v, __shfl_xor(v, m, 64));
    return v;
}

// Exclusive scan of bsum[0..nT) into LDS lb[] (wave 0 only; 3 elems/lane).
// MUST be called by all threads of the block before any early return.
__device__ __forceinline__ void compute_bpre(const unsigned* __restrict__ bsum,
                                             int nT, unsigned* lb) {
    if (threadIdx.x < 64) {
        int l = threadIdx.x;
        unsigned a0 = (3 * l     < nT) ? bsum[3 * l]     : 0u;
        unsigned a1 = (3 * l + 1 < nT) ? bsum[3 * l + 1] : 0u;
        unsigned a2 = (3 * l + 2 < nT) ? bsum[3 * l + 2] : 0u;
        unsigned tot = a0 + a1 + a2, x = tot;
#pragma unroll
        for (int d = 1; d < 64; d <<= 1) {
            unsigned y = __shfl_up(x, d, 64);
            if (l >= d) x += y;
        }
        unsigned excl = x - tot;
        if (3 * l     < nT) lb[3 * l]     = excl;
        if (3 * l + 1 < nT) lb[3 * l + 1] = excl + a0;
        if (3 * l + 2 < nT) lb[3 * l + 2] = excl + a0 + a1;
    }
    __syncthreads();
}

// ---- 1. k_prep: block-range multiplexed {ps/pd | hist+rank} ---------------
__global__ __launch_bounds__(256) void k_prep(
    const float* __restrict__ H, const float* __restrict__ Wa,
    const int* __restrict__ dst,
    float* __restrict__ ps, float* __restrict__ pd,
    unsigned* __restrict__ deg, unsigned* __restrict__ erank,
    int N, int D, int E, int nb_ps) {
    int b = blockIdx.x;
    if (b < nb_ps) {
        // attention projections: one wave per node, float4 loads
        int wid  = b * 4 + (threadIdx.x >> 6);
        int lane = threadIdx.x & 63;
        if (wid >= N) return;
        const float4* row = (const float4*)(H + (size_t)wid * D);
        const float4* wa0 = (const float4*)Wa;
        const float4* wa1 = (const float4*)(Wa + D);   // D%4==0
        int nv = D >> 2;
        float s0 = 0.f, s1 = 0.f;
        for (int v = lane; v < nv; v += 64) {
            float4 h = row[v], a = wa0[v], c = wa1[v];
            s0 += h.x * a.x + h.y * a.y + h.z * a.z + h.w * a.w;
            s1 += h.x * c.x + h.y * c.y + h.z * c.z + h.w * c.w;
        }
        s0 = wrsum(s0);
        s1 = wrsum(s1);
        if (lane == 0) { ps[wid] = s0; pd[wid] = s1; }
    } else {
        // histogram + per-edge rank (the ONE atomic pass over edges)
        int e = (b - nb_ps) * 256 + threadIdx.x;
        if (e < E) erank[e] = atomicAdd(&deg[dst[e]], 1u);
    }
}

// ---- 2. per-tile exclusive scan -------------------------------------------
// loffs[i] = exclusive prefix of deg within i's 1024-tile; bsum[tile] = total.
__global__ __launch_bounds__(256) void k_scan1(
    const unsigned* __restrict__ deg, unsigned* __restrict__ loffs,
    unsigned* __restrict__ bsum, int N) {
    __shared__ unsigned wsum[4];
    int t = threadIdx.x, b = blockIdx.x;
    int base = b * 1024 + t * 4;
    unsigned v[4];
#pragma unroll
    for (int j = 0; j < 4; j++) { int i = base + j; v[j] = (i < N) ? deg[i] : 0u; }
    unsigned p0 = v[0], p1 = p0 + v[1], p2 = p1 + v[2];
    unsigned tot = p2 + v[3];
    unsigned x = tot;
    int lane = t & 63, w = t >> 6;
#pragma unroll
    for (int d = 1; d < 64; d <<= 1) { unsigned y = __shfl_up(x, d, 64); if (lane >= d) x += y; }
    if (lane == 63) wsum[w] = x;
    __syncthreads();
    unsigned woff = 0;
    for (int i = 0; i < w; i++) woff += wsum[i];
    unsigned excl = woff + x - tot;   // exclusive prefix of this thread's 4 elems
    unsigned o[4] = {excl, excl + p0, excl + p1, excl + p2};
#pragma unroll
    for (int j = 0; j < 4; j++) { int i = base + j; if (i < N) loffs[i] = o[j]; }
    if (t == 255) bsum[b] = excl + tot;  // tile total
}

// ---- 3. scatter edges into dst-sorted order (NO atomics) ------------------
__global__ __launch_bounds__(256) void k_scatter(
    const int* __restrict__ src, const int* __restrict__ dst,
    const unsigned* __restrict__ loffs, const unsigned* __restrict__ bsum,
    const unsigned* __restrict__ erank,
    int* __restrict__ ssrc, int E, int nT) {
    __shared__ unsigned lb[MAXT];
    compute_bpre(bsum, nT, lb);
    int e = blockIdx.x * 256 + threadIdx.x;
    if (e >= E) return;
    int d = dst[e];
    ssrc[loffs[d] + lb[d >> 10] + erank[e]] = src[e];
}

// ---- 4. fused softmax + weighted segment_max + gate + graph-sum -----------
// One wave per KNODES consecutive dst nodes. Lane owns float4 #lane and
// (if q1) float4 #(64+lane). Requires D%4==0, D<=512.
__global__ __launch_bounds__(256) void k_fused(
    const float* __restrict__ H, const float* __restrict__ eta,
    const float* __restrict__ ps, const float* __restrict__ pd,
    const float* __restrict__ battn,
    const unsigned* __restrict__ loffs, const unsigned* __restrict__ bsum,
    const int* __restrict__ ssrc, const int* __restrict__ gid,
    float* __restrict__ hg, int N, int D, int E, int nT) {
    __shared__ unsigned lb[MAXT];
    compute_bpre(bsum, nT, lb);          // all threads reach the sync inside

    int wid  = (blockIdx.x * blockDim.x + threadIdx.x) >> 6;
    int lane = threadIdx.x & 63;
    int n0 = wid * KNODES;
    if (n0 >= N) return;
    int n1 = min(n0 + KNODES, N);
    int nv = D >> 2;
    bool q0 = lane < nv;
    bool q1 = (64 + lane) < nv;
    float b0 = battn[0];

    float sx = 0.f, sy = 0.f, sz = 0.f, sw = 0.f;
    float tx = 0.f, ty = 0.f, tz = 0.f, tw = 0.f;
    int curg = gid[n0];

    for (int n = n0; n < n1; ++n) {
        unsigned e0 = loffs[n] + lb[n >> 10];
        unsigned e1 = (n + 1 < N) ? (loffs[n + 1] + lb[(n + 1) >> 10]) : (unsigned)E;
        int degn = (int)(e1 - e0);
        const float4* hrow = (const float4*)(H + (size_t)n * D);
        float4 h0 = {0, 0, 0, 0}, h1 = {0, 0, 0, 0};
        if (q0) h0 = hrow[lane];
        if (q1) h1 = hrow[64 + lane];
        float hx = h0.x, hy = h0.y, hz = h0.z, hw = h0.w;
        float gx = h1.x, gy = h1.y, gz = h1.z, gw = h1.w;
        if (degn > 0) {
            float pdn = pd[n] + b0;
            float ax = -INFINITY, ay = -INFINITY, az = -INFINITY, aw = -INFINITY;
            float bx = -INFINITY, by = -INFINITY, bz = -INFINITY, bw = -INFINITY;
            if (degn <= 64) {
                // lane-parallel softmax, one edge per lane
                int   sn_l = (lane < degn) ? ssrc[e0 + lane] : 0;
                float w_l  = (lane < degn) ? lrelu(ps[sn_l] + pdn) : -INFINITY;
                float m    = wrmax(w_l);
                float ex   = (lane < degn) ? expf(w_l - m) : 0.f;
                float s    = wrsum(ex);
                float a_l  = ex * (1.f / s);
                // 2x-unrolled edge loop (measured best vs 4x: occupancy)
                int e = 0;
                for (; e + 1 < degn; e += 2) {
                    float a0s = __shfl(a_l, e, 64), a1s = __shfl(a_l, e + 1, 64);
                    int   s0i = __shfl(sn_l, e, 64), s1i = __shfl(sn_l, e + 1, 64);
                    const float4* r0 = (const float4*)(H + (size_t)s0i * D);
                    const float4* r1 = (const float4*)(H + (size_t)s1i * D);
                    if (q0) {
                        float4 u = r0[lane];
                        float4 v = r1[lane];
                        ax = fmaxf(fmaxf(ax, a0s * u.x), a1s * v.x);
                        ay = fmaxf(fmaxf(ay, a0s * u.y), a1s * v.y);
                        az = fmaxf(fmaxf(az, a0s * u.z), a1s * v.z);
                        aw = fmaxf(fmaxf(aw, a0s * u.w), a1s * v.w);
                    }
                    if (q1) {
                        float4 u = r0[64 + lane];
                        float4 v = r1[64 + lane];
                        bx = fmaxf(fmaxf(bx, a0s * u.x), a1s * v.x);
                        by = fmaxf(fmaxf(by, a0s * u.y), a1s * v.y);
                        bz = fmaxf(fmaxf(bz, a0s * u.z), a1s * v.z);
                        bw = fmaxf(fmaxf(bw, a0s * u.w), a1s * v.w);
                    }
                }
                if (e < degn) {
                    float a  = __shfl(a_l, e, 64);
                    int   sn = __shfl(sn_l, e, 64);
                    const float4* srow = (const float4*)(H + (size_t)sn * D);
                    if (q0) {
                        float4 v0 = srow[lane];
                        ax = fmaxf(ax, a * v0.x); ay = fmaxf(ay, a * v0.y);
                        az = fmaxf(az, a * v0.z); aw = fmaxf(aw, a * v0.w);
                    }
                    if (q1) {
                        float4 v1 = srow[64 + lane];
                        bx = fmaxf(bx, a * v1.x); by = fmaxf(by, a * v1.y);
                        bz = fmaxf(bz, a * v1.z); bw = fmaxf(bw, a * v1.w);
                    }
                }
            } else {
                // rare high-degree fallback: recompute scores
                float mm = -INFINITY;
                for (unsigned e = e0 + lane; e < e1; e += 64)
                    mm = fmaxf(mm, lrelu(ps[ssrc[e]] + pdn));
                float m = wrmax(mm);
                float ssum = 0.f;
                for (unsigned e = e0 + lane; e < e1; e += 64)
                    ssum += expf(lrelu(ps[ssrc[e]] + pdn) - m);
                float s = wrsum(ssum), inv = 1.f / s;
                for (unsigned e = e0; e < e1; ++e) {
                    int sn = ssrc[e];
                    float a = expf(lrelu(ps[sn] + pdn) - m) * inv;
                    const float4* srow = (const float4*)(H + (size_t)sn * D);
                    if (q0) {
                        float4 v0 = srow[lane];
                        ax = fmaxf(ax, a * v0.x); ay = fmaxf(ay, a * v0.y);
                        az = fmaxf(az, a * v0.z); aw = fmaxf(aw, a * v0.w);
                    }
                    if (q1) {
                        float4 v1 = srow[64 + lane];
                        bx = fmaxf(bx, a * v1.x); by = fmaxf(by, a * v1.y);
                        bz = fmaxf(bz, a * v1.z); bw = fmaxf(bw, a * v1.w);
                    }
                }
            }
            float et = eta[n], om = 1.f - et;
            hx = et * h0.x + om * ax; hy = et * h0.y + om * ay;
            hz = et * h0.z + om * az; hw = et * h0.w + om * aw;
            gx = et * h1.x + om * bx; gy = et * h1.y + om * by;
            gz = et * h1.z + om * bz; gw = et * h1.w + om * bw;
        }
        // register graph-sum; flush on graph-id change (gid sorted)
        int g = gid[n];
        if (g != curg) {
            float* row = hg + (size_t)curg * D;
            int c = 4 * lane;
            if (q0) {
                atomicAdd(&row[c + 0], sx); atomicAdd(&row[c + 1], sy);
                atomicAdd(&row[c + 2], sz); atomicAdd(&row[c + 3], sw);
            }
            if (q1) {
                int c1 = 4 * (64 + lane);
                atomicAdd(&row[c1 + 0], tx); atomicAdd(&row[c1 + 1], ty);
                atomicAdd(&row[c1 + 2], tz); atomicAdd(&row[c1 + 3], tw);
            }
            sx = sy = sz = sw = tx = ty = tz = tw = 0.f;
            curg = g;
        }
        sx += hx; sy += hy; sz += hz; sw += hw;
        if (q1) { tx += gx; ty += gy; tz += gz; tw += gw; }
    }
    float* row = hg + (size_t)curg * D;
    int c = 4 * lane;
    if (q0) {
        atomicAdd(&row[c + 0], sx); atomicAdd(&row[c + 1], sy);
        atomicAdd(&row[c + 2], sz); atomicAdd(&row[c + 3], sw);
    }
    if (q1) {
        int c1 = 4 * (64 + lane);
        atomicAdd(&row[c1 + 0], tx); atomicAdd(&row[c1 + 1], ty);
        atomicAdd(&row[c1 + 2], tz); atomicAdd(&row[c1 + 3], tw);
    }
}

// ---- 5. classifier: 4 waves split D, LDS reduce (C<=64) -------------------
__global__ __launch_bounds__(256) void k_out(
    const float* __restrict__ hg, const float* __restrict__ Wl,
    const float* __restrict__ bl, float* __restrict__ out,
    int D, int C) {
    __shared__ float part[4][64];
    int b = blockIdx.x;
    int w = threadIdx.x >> 6, l = threadIdx.x & 63;
    float acc = 0.f;
    if (l < C) {
        const float* row = hg + (size_t)b * D;
        for (int d = w; d < D; d += 4)
            acc += lrelu(row[d]) * Wl[(size_t)d * C + l];
        part[w][l] = acc;
    }
    __syncthreads();
    int c = threadIdx.x;
    if (c < C)
        out[(size_t)b * C + c] =
            part[0][c] + part[1][c] + part[2][c] + part[3][c] + bl[c];
}

// ---------------------------------------------------------------------------
extern "C" void kernel_launch(void* const* d_in, const int* in_sizes, int n_in,
                              void* d_out, int out_size, void* d_ws, size_t ws_size,
                              hipStream_t stream) {
    const float* H   = (const float*)d_in[0];
    const float* eta = (const float*)d_in[1];
    const float* Wa  = (const float*)d_in[2];
    const float* ba  = (const float*)d_in[3];
    const float* Wl  = (const float*)d_in[4];
    const float* bl  = (const float*)d_in[5];
    const int*   src = (const int*)d_in[6];
    const int*   dst = (const int*)d_in[7];
    const int*   gid = (const int*)d_in[8];

    const int N = in_sizes[1];          // eta is [N,1]
    const int D = in_sizes[2] / 2;      // W_attn is [2D,1]
    const int C = in_sizes[5];          // b_lin is [C]
    const int E = in_sizes[6];          // src is [E]
    const int B = out_size / C;         // out is [B,C]

    // workspace layout (~10 MB): ps pd | deg hg (memset) | loffs bsum ssrc erank
    char* w = (char*)d_ws;
    float*    ps    = (float*)w;    w += (size_t)N * 4;
    float*    pd    = (float*)w;    w += (size_t)N * 4;
    unsigned* deg   = (unsigned*)w; w += (size_t)N * 4;     // memset-zeroed
    float*    hg    = (float*)w;    w += (size_t)B * D * 4; // memset-zeroed
    unsigned* loffs = (unsigned*)w; w += (size_t)N * 4;
    unsigned* bsum  = (unsigned*)w; w += 256 * 4;           // nT <= MAXT=192
    int*      ssrc  = (int*)w;      w += (size_t)E * 4;
    unsigned* erank = (unsigned*)w; w += (size_t)E * 4;

    // deg and hg are contiguous -> single memset
    hipMemsetAsync(deg, 0, ((size_t)N + (size_t)B * D) * 4, stream);

    const int nT      = (N + 1023) / 1024;   // requires nT <= MAXT
    const int nb_ps   = (N + 3) / 4;
    const int nb_hist = (E + 255) / 256;

    k_prep<<<dim3(nb_ps + nb_hist), dim3(256), 0, stream>>>(
        H, Wa, dst, ps, pd, deg, erank, N, D, E, nb_ps);
    k_scan1<<<dim3(nT), dim3(256), 0, stream>>>(deg, loffs, bsum, N);
    k_scatter<<<dim3((E + 255) / 256), dim3(256), 0, stream>>>(
        src, dst, loffs, bsum, erank, ssrc, E, nT);
    {
        int waves  = (N + KNODES - 1) / KNODES;
        int blocks = (waves + 3) / 4;   // 4 waves per 256-thread block
        k_fused<<<dim3(blocks), dim3(256), 0, stream>>>(
            H, eta, ps, pd, ba, loffs, bsum, ssrc, gid, hg, N, D, E, nT);
    }
    k_out<<<dim3(B), dim3(256), 0, stream>>>(hg, Wl, bl, (float*)d_out, D, C);
}